// Round 1
// baseline (364.185 us; speedup 1.0000x reference)
//
#include <hip/hip_runtime.h>

#define NTOK 4608   // token axis N = H*W/2
#define CCH  64     // feature axis C
#define HWSZ 9216   // H*W
#define NB   4      // batch

typedef unsigned short u16;
typedef __attribute__((ext_vector_type(8))) short s16x8;   // 8 bf16 (4 VGPRs)
typedef __attribute__((ext_vector_type(4))) float f32x4;

__device__ __forceinline__ f32x4 mfma16(s16x8 a, s16x8 b, f32x4 c){
  return __builtin_amdgcn_mfma_f32_16x16x32_bf16(a, b, c, 0, 0, 0);
}

__device__ __forceinline__ u16 f2bf(float f){
  unsigned int u = __float_as_uint(f);
  u += 0x7fffu + ((u >> 16) & 1u);   // RNE
  return (u16)(u >> 16);
}

// ---------------------------------------------------------------------------
// Kernel 1: theta (from y) and phi (from x) projections.
// Output layout: TH/PH[b][pos][c] bf16, pos in [0,4608), c in [0,64).
// value(pos,c) = sum_k w[c>>1][k] * src[b][k][(c&1)*4608 + pos]
// Block: 256 thr = 64 pos-lanes x 4 c-quarters (16 c each). Weights are
// wave-uniform -> s_loads. src loads are lane-coalesced (consecutive pos).
// ---------------------------------------------------------------------------
__global__ __launch_bounds__(256) void proj_nc_kernel(
    const float* __restrict__ x, const float* __restrict__ y,
    const float* __restrict__ w_phi, const float* __restrict__ w_theta,
    u16* __restrict__ TH, u16* __restrict__ PH){
  const int b = blockIdx.y;
  const int n = blockIdx.x*64 + (threadIdx.x & 63);
  const int q = __builtin_amdgcn_readfirstlane((int)(threadIdx.x >> 6));
  const float* xb = x + (size_t)b*CCH*HWSZ;
  const float* yb = y + (size_t)b*CCH*HWSZ;
  const float* wp = w_phi   + q*8*CCH;
  const float* wt = w_theta + q*8*CCH;
  float accP[16], accT[16];
  #pragma unroll
  for(int j=0;j<16;++j){ accP[j]=0.f; accT[j]=0.f; }
  for(int k=0;k<CCH;++k){
    float xv0 = xb[k*HWSZ + n];
    float xv1 = xb[k*HWSZ + NTOK + n];
    float yv0 = yb[k*HWSZ + n];
    float yv1 = yb[k*HWSZ + NTOK + n];
    #pragma unroll
    for(int j=0;j<16;++j){
      float wpv = wp[(j>>1)*CCH + k];
      float wtv = wt[(j>>1)*CCH + k];
      accP[j] = fmaf(wpv, (j&1)?xv1:xv0, accP[j]);
      accT[j] = fmaf(wtv, (j&1)?yv1:yv0, accT[j]);
    }
  }
  s16x8 vp0, vp1, vt0, vt1;
  #pragma unroll
  for(int j=0;j<8;++j){
    vp0[j] = (short)f2bf(accP[j]);   vp1[j] = (short)f2bf(accP[8+j]);
    vt0[j] = (short)f2bf(accT[j]);   vt1[j] = (short)f2bf(accT[8+j]);
  }
  u16* php = PH + ((size_t)b*NTOK + n)*CCH + q*16;
  u16* thp = TH + ((size_t)b*NTOK + n)*CCH + q*16;
  *(s16x8*)php     = vp0; *(s16x8*)(php+8) = vp1;
  *(s16x8*)thp     = vt0; *(s16x8*)(thp+8) = vt1;
}

// ---------------------------------------------------------------------------
// Kernel 2: g projection, stored c-major: G[b][c][m] bf16 (PV B-fragments
// need 8 contiguous m per lane). Fully coalesced loads and stores.
// ---------------------------------------------------------------------------
__global__ __launch_bounds__(256) void proj_g_kernel(
    const float* __restrict__ x, const float* __restrict__ w_g,
    u16* __restrict__ G){
  const int b = blockIdx.z, c = blockIdx.y;
  const int m = blockIdx.x*256 + threadIdx.x;
  const float* xb = x + (size_t)b*CCH*HWSZ + (c&1)*NTOK + m;
  const float* wg = w_g + (c>>1)*CCH;        // uniform -> scalar loads
  float a = 0.f;
  for(int k=0;k<CCH;++k) a = fmaf(wg[k], xb[(size_t)k*HWSZ], a);
  G[((size_t)b*CCH + c)*NTOK + m] = f2bf(a);
}

// ---------------------------------------------------------------------------
// Kernel 3: pass A — per-column (m) online max/sumexp of S = theta^T phi.
// Each wave owns 16 m-columns (B-fragment loop-invariant in registers) and
// sweeps half the n-range in 64-row steps (2 n-halves for TLP).
// C layout: col = lane&15, row = (lane>>4)*4 + reg  [m89-verified].
// Stats kept per-lane (covering its own rows), merged via shfl_xor(16,32).
// ---------------------------------------------------------------------------
__global__ __launch_bounds__(256) void passA_kernel(
    const u16* __restrict__ TH, const u16* __restrict__ PH,
    float* __restrict__ CMAXP, float* __restrict__ CSUMP){
  const int lane = threadIdx.x & 63, wave = threadIdx.x >> 6;
  const int b = blockIdx.z, half = blockIdx.y;
  const int mbase = blockIdx.x*64 + wave*16;
  const int l15 = lane & 15, lg = lane >> 4;
  const u16* thb = TH + (size_t)b*NTOK*CCH;
  const u16* phb = PH + (size_t)b*NTOK*CCH;
  const u16* brow = phb + (size_t)(mbase + l15)*CCH + lg*8;
  s16x8 bf0 = *(const s16x8*)(brow);
  s16x8 bf1 = *(const s16x8*)(brow + 32);
  float rm = -3.0e38f, rs = 0.f;
  const int n0 = half*(NTOK/2), n1 = n0 + (NTOK/2);
  for(int n = n0; n < n1; n += 64){
    float v[16];
    #pragma unroll
    for(int s=0;s<4;++s){
      const u16* arow = thb + (size_t)(n + s*16 + l15)*CCH + lg*8;
      s16x8 a0 = *(const s16x8*)(arow);
      s16x8 a1 = *(const s16x8*)(arow + 32);
      f32x4 acc = {0.f,0.f,0.f,0.f};
      acc = mfma16(a0, bf0, acc);
      acc = mfma16(a1, bf1, acc);
      v[s*4+0]=acc[0]; v[s*4+1]=acc[1]; v[s*4+2]=acc[2]; v[s*4+3]=acc[3];
    }
    float vm = v[0];
    #pragma unroll
    for(int i=1;i<16;++i) vm = fmaxf(vm, v[i]);
    if(vm > rm){ rs *= __expf(rm - vm); rm = vm; }
    float add = 0.f;
    #pragma unroll
    for(int i=0;i<16;++i) add += __expf(v[i] - rm);
    rs += add;
  }
  // merge lane groups (same column, different row subsets)
  #pragma unroll
  for(int off=16; off<=32; off<<=1){
    float om = __shfl_xor(rm, off);
    float os = __shfl_xor(rs, off);
    float nm = fmaxf(rm, om);
    rs = rs*__expf(rm - nm) + os*__expf(om - nm);
    rm = nm;
  }
  if(lg == 0){
    const int idx = (half*NB + b)*NTOK + mbase + l15;
    CMAXP[idx] = rm;
    CSUMP[idx] = rs;
  }
}

// ---------------------------------------------------------------------------
// Kernel 4: merge the two n-half stats; store max and 1/sum.
// ---------------------------------------------------------------------------
__global__ __launch_bounds__(256) void merge_stats_kernel(
    const float* __restrict__ CMAXP, const float* __restrict__ CSUMP,
    float* __restrict__ CMAX, float* __restrict__ CINV){
  const int i = blockIdx.x*256 + threadIdx.x;
  if(i >= NB*NTOK) return;
  float m0 = CMAXP[i], m1 = CMAXP[NB*NTOK + i];
  float s0 = CSUMP[i], s1 = CSUMP[NB*NTOK + i];
  float M = fmaxf(m0, m1);
  float s = s0*__expf(m0 - M) + s1*__expf(m1 - M);
  CMAX[i] = M;
  CINV[i] = 1.0f / s;
}

// ---------------------------------------------------------------------------
// Kernel 5: pass B — recompute S tile (bit-identical to pass A), apply
// P = exp(S - M_col) * inv_col, re-layout P via wave-private padded LDS
// (stride 72 shorts -> <=2-way bank aliasing on b128 reads), then
// OUT[n,c] += P @ G. Partial over an m-half; fp32 partials summed later.
// ---------------------------------------------------------------------------
__global__ __launch_bounds__(256) void passB_kernel(
    const u16* __restrict__ TH, const u16* __restrict__ PH,
    const u16* __restrict__ G,
    const float* __restrict__ CMAX, const float* __restrict__ CINV,
    float* __restrict__ OUTP, int mcount){
  __shared__ u16 plds[4][16*72];
  const int lane = threadIdx.x & 63, wave = threadIdx.x >> 6;
  const int b = blockIdx.z, half = blockIdx.y;
  const int nbase = blockIdx.x*64 + wave*16;
  const int l15 = lane & 15, lg = lane >> 4;
  const u16* thb = TH + (size_t)b*NTOK*CCH;
  const u16* phb = PH + (size_t)b*NTOK*CCH;
  const u16* gbb = G  + (size_t)b*CCH*NTOK;  // [c][m]
  const float* cmax = CMAX + (size_t)b*NTOK;
  const float* cinv = CINV + (size_t)b*NTOK;
  const u16* arow = thb + (size_t)(nbase + l15)*CCH + lg*8;
  s16x8 a0 = *(const s16x8*)(arow);
  s16x8 a1 = *(const s16x8*)(arow + 32);
  f32x4 acc[4];
  #pragma unroll
  for(int ct=0;ct<4;++ct) acc[ct] = (f32x4){0.f,0.f,0.f,0.f};
  u16* myp = plds[wave];
  const int m0 = half*mcount, m1 = m0 + mcount;
  for(int m = m0; m < m1; m += 64){
    #pragma unroll
    for(int s=0;s<4;++s){
      const int col = m + s*16 + l15;
      const u16* brow = phb + (size_t)col*CCH + lg*8;
      s16x8 b0 = *(const s16x8*)(brow);
      s16x8 b1 = *(const s16x8*)(brow + 32);
      f32x4 sa = {0.f,0.f,0.f,0.f};
      sa = mfma16(a0, b0, sa);
      sa = mfma16(a1, b1, sa);
      const float cm = cmax[col], ci = cinv[col];
      #pragma unroll
      for(int r=0;r<4;++r){
        float p = __expf(sa[r] - cm) * ci;
        myp[(lg*4 + r)*72 + s*16 + l15] = f2bf(p);
      }
    }
    __syncthreads();   // P write -> P read (cheap insurance; wave-private)
    s16x8 pa0 = *(const s16x8*)(myp + l15*72 + lg*8);
    s16x8 pa1 = *(const s16x8*)(myp + l15*72 + lg*8 + 32);
    #pragma unroll
    for(int ct=0;ct<4;++ct){
      const u16* grow = gbb + (size_t)(ct*16 + l15)*NTOK + m + lg*8;
      s16x8 g0 = *(const s16x8*)(grow);
      s16x8 g1 = *(const s16x8*)(grow + 32);
      acc[ct] = mfma16(pa0, g0, acc[ct]);
      acc[ct] = mfma16(pa1, g1, acc[ct]);
    }
  }
  float* outp = OUTP + ((size_t)(half*NB + b)*NTOK)*CCH;
  #pragma unroll
  for(int ct=0;ct<4;++ct)
    #pragma unroll
    for(int r=0;r<4;++r)
      outp[(size_t)(nbase + lg*4 + r)*CCH + ct*16 + l15] = acc[ct][r];
}

// ---------------------------------------------------------------------------
// Kernel 6: sum m-partials, apply w_mask 1x1 conv (weights wave-uniform ->
// s_loads), add x. out4[b][ic][p] = OUT[b][p%4608][2*ic + (p>=4608)].
// ---------------------------------------------------------------------------
__global__ __launch_bounds__(256) void finalize_kernel(
    const float* __restrict__ OUTP, const float* __restrict__ w_mask,
    const float* __restrict__ x, float* __restrict__ out, int msplit){
  const int b = blockIdx.z, hi = blockIdx.y;
  const int n = blockIdx.x*64 + (threadIdx.x & 63);
  const int q = __builtin_amdgcn_readfirstlane((int)(threadIdx.x >> 6));
  float v[32];
  #pragma unroll
  for(int ic=0;ic<32;++ic) v[ic] = 0.f;
  for(int h=0; h<msplit; ++h){
    const float* r = OUTP + ((size_t)(h*NB + b)*NTOK + n)*CCH;
    #pragma unroll
    for(int ic=0;ic<32;++ic) v[ic] += r[2*ic + hi];
  }
  const float* wm = w_mask + q*16*32;
  const int pbase = hi*NTOK + n;
  #pragma unroll
  for(int j=0;j<16;++j){
    float a = 0.f;
    #pragma unroll
    for(int ic=0;ic<32;++ic) a = fmaf(wm[j*32 + ic], v[ic], a);
    const size_t idx = ((size_t)b*CCH + q*16 + j)*HWSZ + pbase;
    out[idx] = a + x[idx];
  }
}

// ---------------------------------------------------------------------------
extern "C" void kernel_launch(void* const* d_in, const int* in_sizes, int n_in,
                              void* d_out, int out_size, void* d_ws, size_t ws_size,
                              hipStream_t stream){
  const float* x       = (const float*)d_in[0];
  const float* y       = (const float*)d_in[1];
  const float* w_phi   = (const float*)d_in[2];
  const float* w_theta = (const float*)d_in[3];
  const float* w_g     = (const float*)d_in[4];
  const float* w_mask  = (const float*)d_in[5];
  float* out = (float*)d_out;
  char* ws = (char*)d_ws;

  const size_t projB = (size_t)NB*NTOK*CCH*sizeof(u16);      // 2,359,296
  const size_t outpB1 = (size_t)NB*NTOK*CCH*sizeof(float);   // 4,718,592 per split
  const size_t statB = (size_t)2*NB*NTOK*sizeof(float);      // 147,456 (2 halves)
  const size_t fstatB = (size_t)NB*NTOK*sizeof(float);       // 73,728

  // m-split of pass B doubles wave-level parallelism; needs 2x fp32 partials.
  int msplit = (ws_size >= 3*projB + 2*outpB1 + 2*statB + 2*fstatB) ? 2 : 1;

  size_t off = 0;
  u16*   TH    = (u16*)(ws + off); off += projB;
  u16*   PH    = (u16*)(ws + off); off += projB;
  u16*   G     = (u16*)(ws + off); off += projB;
  float* OUTP  = (float*)(ws + off); off += (size_t)msplit*outpB1;
  float* CMAXP = (float*)(ws + off); off += statB;
  float* CSUMP = (float*)(ws + off); off += statB;
  float* CMAX  = (float*)(ws + off); off += fstatB;
  float* CINV  = (float*)(ws + off); off += fstatB;

  proj_nc_kernel<<<dim3(NTOK/64, NB), 256, 0, stream>>>(x, y, w_phi, w_theta, TH, PH);
  proj_g_kernel<<<dim3(NTOK/256, CCH, NB), 256, 0, stream>>>(x, w_g, G);
  passA_kernel<<<dim3(NTOK/64, 2, NB), 256, 0, stream>>>(TH, PH, CMAXP, CSUMP);
  merge_stats_kernel<<<dim3((NB*NTOK)/256), 256, 0, stream>>>(CMAXP, CSUMP, CMAX, CINV);
  passB_kernel<<<dim3(NTOK/64, msplit, NB), 256, 0, stream>>>(TH, PH, G, CMAX, CINV,
                                                              OUTP, NTOK/msplit);
  finalize_kernel<<<dim3(NTOK/64, 2, NB), 256, 0, stream>>>(OUTP, w_mask, x, out, msplit);
}